// Round 10
// baseline (718.162 us; speedup 1.0000x reference)
//
#include <hip/hip_runtime.h>
#include <hip/hip_bf16.h>
#include <hip/hip_fp16.h>

#define WIDTH 1024
#define BATCH 8192

typedef __attribute__((ext_vector_type(8))) short short8;
typedef __attribute__((ext_vector_type(8))) _Float16 half8;
typedef __attribute__((ext_vector_type(4))) float floatx4;

typedef __attribute__((address_space(1))) void gvoid;
typedef __attribute__((address_space(3))) void lvoid;

__device__ __forceinline__ void async_copy16(const void* g, void* l) {
    __builtin_amdgcn_global_load_lds((gvoid*)g, (lvoid*)l, 16, 0, 0);
}

// bf16 hi/lo split store (residual exactly representable - no denormal risk)
__device__ __forceinline__ void split_store(float v, __hip_bfloat16* hi, __hip_bfloat16* lo, long idx) {
    __hip_bfloat16 h = __float2bfloat16(v);
    hi[idx] = h;
    lo[idx] = __float2bfloat16(v - __bfloat162float(h));
}

__device__ __forceinline__ floatx4 mfma16(short8 a, short8 b, floatx4 c) {
    return __builtin_amdgcn_mfma_f32_16x16x32_f16(
        __builtin_bit_cast(half8, a), __builtin_bit_cast(half8, b), c, 0, 0, 0);
}
__device__ __forceinline__ floatx4 mfmabf(short8 a, short8 b, floatx4 c) {
    return __builtin_amdgcn_mfma_f32_16x16x32_bf16(a, b, c, 0, 0, 0);
}

template<int N> __device__ __forceinline__ void waitv() {
    if constexpr (N == 0)       asm volatile("s_waitcnt vmcnt(0)" ::: "memory");
    else if constexpr (N == 4)  asm volatile("s_waitcnt vmcnt(4)" ::: "memory");
    else if constexpr (N == 6)  asm volatile("s_waitcnt vmcnt(6)" ::: "memory");
    else if constexpr (N == 8)  asm volatile("s_waitcnt vmcnt(8)" ::: "memory");
}

// T2 swizzle (verified: bank conflicts -> 0)
__device__ __forceinline__ int swz_col(int s) {
    return ((s & 3) ^ ((s >> 3) & 3)) << 3;
}

// T1 XCD co-location map (verified r6: FETCH -30%)
__device__ __forceinline__ void xcd_map(int idx, int nm, int& bm, int& bn) {
    if ((nm & 7) == 0) {
        bm = (idx & 7) | ((idx >> 5) << 3);
        bn = (idx >> 3) & 3;
    } else {
        bm = idx >> 2;
        bn = idx & 3;
    }
}

// ---------------- transpose W_h (fp32) -> Wt bf16-split (Y path) + f16 (D path) ----------------
__global__ __launch_bounds__(256) void transpose_k(
    const float* __restrict__ W,
    __hip_bfloat16* __restrict__ Wthb, __hip_bfloat16* __restrict__ Wtlb,
    __half* __restrict__ Wtf)
{
    __shared__ float t[32][33];
    const int tx = threadIdx.x & 31, ty = threadIdx.x >> 5;
    const int bx = blockIdx.x << 5, by = blockIdx.y << 5;
#pragma unroll
    for (int r = 0; r < 32; r += 8)
        t[ty + r][tx] = W[(long)(by + ty + r) * WIDTH + bx + tx];
    __syncthreads();
#pragma unroll
    for (int r = 0; r < 32; r += 8) {
        const float v = t[tx][ty + r];
        const long idx = (long)(bx + ty + r) * WIDTH + by + tx;
        split_store(v, Wthb, Wtlb, idx);
        Wtf[idx] = __float2half(v);
    }
}

// ---------------- pack head weights: Wcat[32][1024] bf16-split + f16 ----------------
__global__ __launch_bounds__(256) void buildwcat_k(
    const float* __restrict__ W_ld, const float* __restrict__ W_lo,
    const float* __restrict__ W_g,
    __hip_bfloat16* __restrict__ Wchb, __hip_bfloat16* __restrict__ Wclb,
    __half* __restrict__ Wcf)
{
    const int idx = blockIdx.x * 256 + threadIdx.x;   // 32*1024
    const int n = idx >> 10, k = idx & 1023;
    float v = 0.f;
    if (n < 7)       v = W_ld[k * 7 + n];
    else if (n < 28) v = W_lo[k * 21 + (n - 7)];
    else if (n == 28) v = W_g[k];
    split_store(v, Wchb, Wclb, idx);
    Wcf[idx] = __float2half(v);
}

// ---------------- layer 1: Y1 bf16-split, D1 f16 ----------------
__global__ __launch_bounds__(256) void prep_k(
    const float* __restrict__ state,
    const float* __restrict__ W_in,
    const float* __restrict__ b_in,
    __hip_bfloat16* __restrict__ Y1h, __hip_bfloat16* __restrict__ Y1l,
    __half* __restrict__ D1f)
{
    const int b = blockIdx.x;
    const int j0 = threadIdx.x * 4;
    float s[7];
#pragma unroll
    for (int d = 0; d < 7; ++d) s[d] = state[b * 7 + d];
    float a[4];
#pragma unroll
    for (int q = 0; q < 4; ++q) a[q] = b_in[j0 + q];
    float w[7][4];
#pragma unroll
    for (int d = 0; d < 7; ++d)
#pragma unroll
        for (int q = 0; q < 4; ++q) {
            w[d][q] = W_in[d * WIDTH + j0 + q];
            a[q] += s[d] * w[d][q];
        }
    bool gp[4];
#pragma unroll
    for (int q = 0; q < 4; ++q) {
        gp[q] = a[q] > 0.f;
        split_store(gp[q] ? a[q] : 0.f, Y1h, Y1l, (long)b * WIDTH + j0 + q);
    }
    union { unsigned long long u64; unsigned short h[4]; } pk;
#pragma unroll
    for (int d = 0; d < 7; ++d) {
#pragma unroll
        for (int q = 0; q < 4; ++q) {
            __half v = __float2half(gp[q] ? w[d][q] : 0.f);
            pk.h[q] = *reinterpret_cast<unsigned short*>(&v);
        }
        *reinterpret_cast<unsigned long long*>(&D1f[((long)b * 7 + d) * WIDTH + j0]) = pk.u64;
    }
}

// ---------------- 512-thread staging primitives (T2 pre-swizzled source) ----------------
__device__ __forceinline__ void st128(const short* src, short* region, int tid, int kbase) {
    async_copy16(src + (long)(tid >> 2) * WIDTH + kbase + swz_col(tid),
                 region + ((tid & 0x1C0) << 3));
}
__device__ __forceinline__ void st256(const short* src, short* region, int tid, int kbase) {
#pragma unroll
    for (int j = 0; j < 2; ++j) {
        const int idx = tid + (j << 9);
        async_copy16(src + (long)(idx >> 2) * WIDTH + kbase + swz_col(idx),
                     region + (((tid & 0x1C0) + (j << 9)) << 3));
    }
}

// ================= y8: 128x256 3-term bf16 GEMM, reg-pipelined, 3-buffer ring (r7-proven) =================
// Ledger: stage = 6 vm events, lookahead 3; steady wait vmcnt(6) keeps only
// stage(c+3) outstanding => stage(c+2) landed before chunk c+1 reads it.
__device__ __forceinline__ void y_stage(
    short* SM, const short* pAh, const short* pAl,
    const short* pBh, const short* pBl, int c, int tid)
{
    short* buf = SM + (c % 3) * 24576;
    const int kb = c * 32;
    st128(pAh, buf,         tid, kb);
    st256(pBh, buf + 8192,  tid, kb);
    st128(pAl, buf + 4096,  tid, kb);
    st256(pBl, buf + 16384, tid, kb);
}

__device__ __forceinline__ void y_reads(
    const short* SM, int c, int wm, int wn, int r, int kqs,
    short8 (&ah)[4], short8 (&al)[4], short8 (&bh)[4], short8 (&bl)[4])
{
    const short* buf = SM + (c % 3) * 24576;
#pragma unroll
    for (int i = 0; i < 4; ++i) {
        ah[i] = *reinterpret_cast<const short8*>(&buf[(wm * 64 + i * 16 + r) * 32 + kqs]);
        al[i] = *reinterpret_cast<const short8*>(&buf[4096 + (wm * 64 + i * 16 + r) * 32 + kqs]);
    }
#pragma unroll
    for (int j = 0; j < 4; ++j) {
        bh[j] = *reinterpret_cast<const short8*>(&buf[8192 + (wn * 64 + j * 16 + r) * 32 + kqs]);
        bl[j] = *reinterpret_cast<const short8*>(&buf[16384 + (wn * 64 + j * 16 + r) * 32 + kqs]);
    }
}

__device__ __forceinline__ void y8_gemm_body(
    short* SM,   // 73728 shorts (3 x 24576)
    int bm, int bn, int tid,
    const __hip_bfloat16* Ah_, const __hip_bfloat16* Al_,
    const __hip_bfloat16* Bh_, const __hip_bfloat16* Bl_,
    const float* bias,
    __hip_bfloat16* outh, __hip_bfloat16* outl)
{
    const int lane = tid & 63, wv = tid >> 6;
    const int wm = wv >> 2, wn = wv & 3;
    const int r = lane & 15, r4 = (lane >> 4) << 2;
    const int kqs = (((lane >> 4) ^ ((r >> 1) & 3)) << 3);
    const short* pAh = (const short*)Ah_ + (long)bm * 128 * WIDTH;
    const short* pAl = (const short*)Al_ + (long)bm * 128 * WIDTH;
    const short* pBh = (const short*)Bh_ + (long)bn * 256 * WIDTH;
    const short* pBl = (const short*)Bl_ + (long)bn * 256 * WIDTH;

    floatx4 acc[4][4] = {};
    short8 ahA[4], alA[4], bhA[4], blA[4];
    short8 ahB[4], alB[4], bhB[4], blB[4];

    y_stage(SM, pAh, pAl, pBh, pBl, 0, tid);
    y_stage(SM, pAh, pAl, pBh, pBl, 1, tid);
    y_stage(SM, pAh, pAl, pBh, pBl, 2, tid);
    waitv<6>();                                   // chunks 0,1 landed
    __builtin_amdgcn_s_barrier();
    y_reads(SM, 0, wm, wn, r, kqs, ahA, alA, bhA, blA);

    auto chunk = [&](short8 (&cah)[4], short8 (&cal)[4], short8 (&cbh)[4], short8 (&cbl)[4],
                     short8 (&nah)[4], short8 (&nal)[4], short8 (&nbh)[4], short8 (&nbl)[4],
                     int c) {
        __builtin_amdgcn_s_barrier();
        if (c + 3 < 32) y_stage(SM, pAh, pAl, pBh, pBl, c + 3, tid);
        if (c + 1 < 32) y_reads(SM, c + 1, wm, wn, r, kqs, nah, nal, nbh, nbl);
        __builtin_amdgcn_s_setprio(1);
#pragma unroll
        for (int i = 0; i < 4; ++i)
#pragma unroll
            for (int j = 0; j < 4; ++j)
                acc[i][j] = mfmabf(cah[i], cbh[j], acc[i][j]);
#pragma unroll
        for (int i = 0; i < 4; ++i)
#pragma unroll
            for (int j = 0; j < 4; ++j)
                acc[i][j] = mfmabf(cal[i], cbh[j], acc[i][j]);
#pragma unroll
        for (int i = 0; i < 4; ++i)
#pragma unroll
            for (int j = 0; j < 4; ++j)
                acc[i][j] = mfmabf(cah[i], cbl[j], acc[i][j]);
        __builtin_amdgcn_s_setprio(0);
        if (c <= 28) waitv<6>();
        else if (c == 29) waitv<0>();
    };

    for (int t2 = 0; t2 < 16; ++t2) {
        chunk(ahA, alA, bhA, blA, ahB, alB, bhB, blB, 2 * t2);
        chunk(ahB, alB, bhB, blB, ahA, alA, bhA, blA, 2 * t2 + 1);
    }

    // epilogue: bias + relu + split store
#pragma unroll
    for (int i = 0; i < 4; ++i)
#pragma unroll
        for (int j = 0; j < 4; ++j) {
            const int col = bn * 256 + wn * 64 + j * 16 + r;
#pragma unroll
            for (int rr = 0; rr < 4; ++rr) {
                const int row = bm * 128 + wm * 64 + i * 16 + r4 + rr;
                float v = acc[i][j][rr] + bias[col];
                v = v > 0.f ? v : 0.f;
                split_store(v, outh, outl, (long)row * WIDTH + col);
            }
        }
}

// ---------------- Y2 GEMM (standalone, y8, XCD-mapped 1-D grid) ----------------
__global__ __launch_bounds__(512, 2) void gemm_y8(
    const __hip_bfloat16* __restrict__ Ah, const __hip_bfloat16* __restrict__ Al,
    const __hip_bfloat16* __restrict__ Bh, const __hip_bfloat16* __restrict__ Bl,
    const float* __restrict__ bias,
    __hip_bfloat16* __restrict__ outh, __hip_bfloat16* __restrict__ outl,
    int ny)
{
    __shared__ __align__(16) short SM[73728];
    int bm, bn;
    xcd_map(blockIdx.x, ny, bm, bn);
    y8_gemm_body(SM, bm, bn, threadIdx.x, Ah, Al, Bh, Bl, bias, outh, outl);
}

// ================= 8-wave 256x256 1-pass f16 D-GEMM, reg-pipelined, 8-region ring (r7-proven) =================
__device__ __forceinline__ void stage_chunk_d2(
    short* SMbase, const short* __restrict__ A, const short* __restrict__ B,
    int tau, int creg, int tid)
{
    const short* src = (creg & 1) ? B : A;
    const int kbase = (tau << 6) + ((creg >> 1) << 5);
    short* region = SMbase + ((tau & 1) << 15) + (creg << 13);
    const int wvb = tid & 0x1C0;
#pragma unroll
    for (int j = 0; j < 2; ++j) {
        const int idx = tid + (j << 9);
        async_copy16(src + (long)(idx >> 2) * WIDTH + kbase + swz_col(idx),
                     region + ((long)(wvb + (j << 9)) << 3));
    }
}

__device__ __forceinline__ void d_stage(
    short* SM, const short* A, const short* B, int c, int tid)
{
    stage_chunk_d2(SM, A, B, c >> 1, (c & 1) << 1, tid);
    stage_chunk_d2(SM, A, B, c >> 1, ((c & 1) << 1) | 1, tid);
}

__device__ __forceinline__ void d_reads(
    const short* SM, int c, int wm, int wn, int r, int kqs,
    short8 (&af)[8], short8 (&bf)[4])
{
    const short* Ab = SM + (((c >> 1) & 1) << 15) + ((c & 1) << 14);
    const short* Bb = Ab + 8192;
#pragma unroll
    for (int i = 0; i < 8; ++i)
        af[i] = *reinterpret_cast<const short8*>(&Ab[(wm * 128 + i * 16 + r) * 32 + kqs]);
#pragma unroll
    for (int j = 0; j < 4; ++j)
        bf[j] = *reinterpret_cast<const short8*>(&Bb[(wn * 64 + j * 16 + r) * 32 + kqs]);
}

__device__ __forceinline__ void d_gemm_256(
    short* SM, const short* Abase, const short* Bbase, int tid,
    int wm, int wn, int r, int kqs, floatx4 (&acc)[8][4])
{
    short8 afA[8], bfA[4], afB[8], bfB[4];

    d_stage(SM, Abase, Bbase, 0, tid);
    d_stage(SM, Abase, Bbase, 1, tid);
    d_stage(SM, Abase, Bbase, 2, tid);
    d_stage(SM, Abase, Bbase, 3, tid);
    waitv<8>();                                   // chunks 0,1 landed
    __builtin_amdgcn_s_barrier();
    d_reads(SM, 0, wm, wn, r, kqs, afA, bfA);

    auto chunk = [&](short8 (&caf)[8], short8 (&cbf)[4],
                     short8 (&naf)[8], short8 (&nbf)[4], int c) {
        __builtin_amdgcn_s_barrier();
        if (c + 4 < 32) d_stage(SM, Abase, Bbase, c + 4, tid);
        if (c + 1 < 32) d_reads(SM, c + 1, wm, wn, r, kqs, naf, nbf);
        __builtin_amdgcn_s_setprio(1);
#pragma unroll
        for (int i = 0; i < 8; ++i)
#pragma unroll
            for (int j = 0; j < 4; ++j)
                acc[i][j] = mfma16(caf[i], cbf[j], acc[i][j]);
        __builtin_amdgcn_s_setprio(0);
        if (c <= 27) waitv<8>();
        else if (c == 28) waitv<4>();
        else if (c == 29) waitv<0>();
    };

    for (int t2 = 0; t2 < 16; ++t2) {
        chunk(afA, bfA, afB, bfB, 2 * t2);
        chunk(afB, bfB, afA, bfA, 2 * t2 + 1);
    }
}

// ================= fused Y3 (y8, dispatched FIRST) + D2 (f16, XCD-mapped) — r7-proven =================
__global__ __launch_bounds__(512, 2) void d2y3_8p(
    const __half* __restrict__ D1,
    const __half* __restrict__ Wtf,
    const __hip_bfloat16* __restrict__ Wthb, const __hip_bfloat16* __restrict__ Wtlb,
    const __hip_bfloat16* __restrict__ Y2h, const __hip_bfloat16* __restrict__ Y2l,
    const float* __restrict__ bias,
    __half* __restrict__ D2out,
    __hip_bfloat16* __restrict__ Y3h, __hip_bfloat16* __restrict__ Y3l,
    int ny128, int nd2)
{
    __shared__ __align__(16) short SM[73728];   // 144 KiB (y8 ring); D uses first 128 KiB
    const int tid = threadIdx.x;

    if ((int)blockIdx.x < ny128 * 4) {
        int bm, bn;
        xcd_map(blockIdx.x, ny128, bm, bn);
        y8_gemm_body(SM, bm, bn, tid, Y2h, Y2l, Wthb, Wtlb, bias, Y3h, Y3l);
        return;
    }

    const int lane = tid & 63, wv = tid >> 6;
    const int wm = wv >> 2, wn = wv & 3;
    const int r = lane & 15, r4 = (lane >> 4) << 2;
    const int kqs = (((lane >> 4) ^ ((r >> 1) & 3)) << 3);

    int bm, bn;
    xcd_map(blockIdx.x - ny128 * 4, nd2, bm, bn);

    floatx4 acc[8][4] = {};
    d_gemm_256(SM, (const short*)D1 + (long)bm * 256 * WIDTH,
               (const short*)Wtf + (long)bn * 256 * WIDTH, tid, wm, wn, r, kqs, acc);

    // epilogue: relu'(Y2) mask, store f16
#pragma unroll
    for (int i = 0; i < 8; ++i)
#pragma unroll
        for (int j = 0; j < 4; ++j) {
            const int col = bn * 256 + wn * 64 + j * 16 + r;
#pragma unroll
            for (int rr = 0; rr < 4; ++rr) {
                const int row = bm * 256 + wm * 128 + i * 16 + r4 + rr;
                float v = acc[i][j][rr];
                const unsigned brow = (unsigned)row / 7u;
                if (!(__bfloat162float(Y2h[(long)brow * WIDTH + col]) > 0.f)) v = 0.f;
                D2out[(long)row * WIDTH + col] = __float2half(v);
            }
        }
}

// ================= NEW: 4-wave 256x256 f16 D-GEMM, wave tile 128x128, ring-3 (96 KB) =================
// 256 thr / 4 waves (2m x 2n), acc[8][8] (256 VGPR), ~420 VGPR -> 1 wave/SIMD.
// Intensity 64 FLOP/LDS-byte (vs 42.7): per-chunk per-CU ds_read insts 64 (vs 96)
// for the same 310 MFMA cyc -> LDS-read-pipe ceiling ~45-48% (vs ~32%).
// Slot = 32 KB (A[256x32] + B[256x32]), ring-3 = 96 KB, 1 blk/CU.
// Stage = 8 vm events; lookahead 3. Steady wait vmcnt(8): only stage(c+3)
// outstanding => stage(c+2) landed before chunk c+1 reads it (barrier-published).
// Prologue 3 stages + vmcnt(8). Tail: last stage(31)@c28; end-29 vmcnt(0).
// Slot-overwrite margin identical to r7/r9's proven ring-3 pattern.

__device__ __forceinline__ void stR(const short* src, short* region, int tid, int kb) {
    const int wvb = tid & 0xC0;
#pragma unroll
    for (int k = 0; k < 4; ++k) {
        const int idx = tid + (k << 8);
        async_copy16(src + (long)(idx >> 2) * WIDTH + kb + swz_col(idx),
                     region + (((k << 8) + wvb) << 3));
    }
}

__device__ __forceinline__ void d128_stage(short* SM, const short* A, const short* B, int c, int tid) {
    short* slot = SM + (c % 3) * 16384;
    stR(A, slot,        tid, c * 32);
    stR(B, slot + 8192, tid, c * 32);
}

__device__ __forceinline__ void d128_reads(
    const short* SM, int c, int wm, int wn, int r, int kqs,
    short8 (&af)[8], short8 (&bf)[8])
{
    const short* slot = SM + (c % 3) * 16384;
#pragma unroll
    for (int i = 0; i < 8; ++i)
        af[i] = *reinterpret_cast<const short8*>(&slot[(wm * 128 + i * 16 + r) * 32 + kqs]);
#pragma unroll
    for (int j = 0; j < 8; ++j)
        bf[j] = *reinterpret_cast<const short8*>(&slot[8192 + (wn * 128 + j * 16 + r) * 32 + kqs]);
}

__device__ __forceinline__ void d128_gemm(
    short* SM, const short* Abase, const short* Bbase, int tid,
    int wm, int wn, int r, int kqs, floatx4 (&acc)[8][8])
{
    short8 afA[8], bfA[8], afB[8], bfB[8];

    d128_stage(SM, Abase, Bbase, 0, tid);
    d128_stage(SM, Abase, Bbase, 1, tid);
    d128_stage(SM, Abase, Bbase, 2, tid);
    waitv<8>();                                   // chunks 0,1 landed
    __builtin_amdgcn_s_barrier();
    d128_reads(SM, 0, wm, wn, r, kqs, afA, bfA);

    auto chunk = [&](short8 (&caf)[8], short8 (&cbf)[8],
                     short8 (&naf)[8], short8 (&nbf)[8], int c) {
        __builtin_amdgcn_s_barrier();
        if (c + 1 < 32) d128_reads(SM, c + 1, wm, wn, r, kqs, naf, nbf);
        if (c + 3 < 32) d128_stage(SM, Abase, Bbase, c + 3, tid);
        __builtin_amdgcn_s_setprio(1);
#pragma unroll
        for (int i = 0; i < 8; ++i)
#pragma unroll
            for (int j = 0; j < 8; ++j)
                acc[i][j] = mfma16(caf[i], cbf[j], acc[i][j]);
        __builtin_amdgcn_s_setprio(0);
        if (c <= 28) waitv<8>();
        else if (c == 29) waitv<0>();
    };

    for (int t2 = 0; t2 < 16; ++t2) {
        chunk(afA, bfA, afB, bfB, 2 * t2);
        chunk(afB, bfB, afA, bfA, 2 * t2 + 1);
    }
}

// ---------------- heady body (128-row Y3 @ Wcat^T, 3-term bf16, 256-thr) ----------------
__device__ __forceinline__ void heady_half(
    short* SMh, int bm, int tl,
    const __hip_bfloat16* __restrict__ Y3h, const __hip_bfloat16* __restrict__ Y3l,
    const __hip_bfloat16* __restrict__ Wch, const __hip_bfloat16* __restrict__ Wcl,
    float* __restrict__ PY)
{
    short* Ash = SMh;          short* Asl = SMh + 4096;
    short* Bsh = SMh + 8192;   short* Bsl = SMh + 9216;
    const int lane = tl & 63;
    const int wv = tl >> 6;
    const int r = lane & 15, r4 = (lane >> 4) << 2;
    const int kqs = (((lane >> 4) ^ ((r >> 1) & 3)) << 3);
    const int srow = tl >> 2, scol = (tl & 3) << 3;
    const int swc = (((tl & 3) ^ ((srow >> 1) & 3)) << 3);
    const long half = 64l * WIDTH;
    const short* pAh = (const short*)Y3h + (long)(bm * 128 + srow) * WIDTH + swc;
    const short* pAl = (const short*)Y3l + (long)(bm * 128 + srow) * WIDTH + swc;
    const long boff = (long)srow * WIDTH + scol;
    const short* pBh = (const short*)Wch;  const short* pBl = (const short*)Wcl;

    floatx4 acc[2][2] = {};
    for (int kt = 0; kt < WIDTH; kt += 32) {
        short8 gbh, gbl;
        if (tl < 128) {
            gbh = *reinterpret_cast<const short8*>(pBh + boff + kt);
            gbl = *reinterpret_cast<const short8*>(pBl + boff + kt);
        }
        __syncthreads();
        async_copy16(pAh + kt,        Ash + wv * 512);
        async_copy16(pAh + half + kt, Ash + 2048 + wv * 512);
        async_copy16(pAl + kt,        Asl + wv * 512);
        async_copy16(pAl + half + kt, Asl + 2048 + wv * 512);
        if (tl < 128) {
            *reinterpret_cast<short8*>(&Bsh[srow * 32 + swc]) = gbh;
            *reinterpret_cast<short8*>(&Bsl[srow * 32 + swc]) = gbl;
        }
        __syncthreads();
        short8 afh[2], afl[2], bfh[2], bfl[2];
#pragma unroll
        for (int i = 0; i < 2; ++i) {
            const int ar = (wv * 32 + i * 16 + r) * 32 + kqs;
            afh[i] = *reinterpret_cast<const short8*>(&Ash[ar]);
            afl[i] = *reinterpret_cast<const short8*>(&Asl[ar]);
        }
#pragma unroll
        for (int j = 0; j < 2; ++j) {
            const int br = (j * 16 + r) * 32 + kqs;
            bfh[j] = *reinterpret_cast<const short8*>(&Bsh[br]);
            bfl[j] = *reinterpret_cast<const short8*>(&Bsl[br]);
        }
#pragma unroll
        for (int i = 0; i < 2; ++i)
#pragma unroll
            for (int j = 0; j < 2; ++j) {
                acc[i][j] = mfmabf(afh[i], bfh[j], acc[i][j]);
                acc[i][j] = mfmabf(afh[i], bfl[j], acc[i][j]);
                acc[i][j] = mfmabf(afl[i], bfh[j], acc[i][j]);
            }
    }
#pragma unroll
    for (int i = 0; i < 2; ++i)
#pragma unroll
        for (int j = 0; j < 2; ++j)
#pragma unroll
            for (int rr = 0; rr < 4; ++rr) {
                const int row = bm * 128 + wv * 32 + i * 16 + r4 + rr;
                PY[(long)row * 32 + j * 16 + r] = acc[i][j][rr];
            }
}

// ================= NEW d3pd128: D3 (d128 body) + fused PD projection + heady =================
__global__ __launch_bounds__(256, 1) void d3pd128(
    const __half* __restrict__ D2,
    const __half* __restrict__ Wtf,
    const __hip_bfloat16* __restrict__ Y3h, const __hip_bfloat16* __restrict__ Y3l,
    const __half* __restrict__ Wcf,
    const __hip_bfloat16* __restrict__ Wchb, const __hip_bfloat16* __restrict__ Wclb,
    float* __restrict__ PDpart, float* __restrict__ PY,
    int nm, int Mrows)
{
    __shared__ __align__(16) short SM[49152];   // 96 KiB
    const int tid = threadIdx.x;

    if ((int)blockIdx.x >= nm * 4) {
        heady_half(SM, blockIdx.x - nm * 4, tid, Y3h, Y3l, Wchb, Wclb, PY);
        return;
    }

    const int lane = tid & 63, wv = tid >> 6;
    const int wm = wv >> 1, wn = wv & 1;
    const int r = lane & 15, kq = (lane >> 4) << 3, r4 = (lane >> 4) << 2;
    const int kqs = (((lane >> 4) ^ ((r >> 1) & 3)) << 3);
    int bm, bn;
    xcd_map(blockIdx.x, nm, bm, bn);

    floatx4 acc[8][8] = {};
    d128_gemm(SM, (const short*)D2 + (long)bm * 256 * WIDTH,
              (const short*)Wtf + (long)bn * 256 * WIDTH, tid, wm, wn, r, kqs, acc);

    // ---- fused PD projection: two col-half rounds through LDS (f16 T, f16 Wc) ----
    short* T   = SM;             // 256 x 136 = 34816 shorts
    short* WcH = SM + 34816;     // 32 x 136  =  4352 shorts

    floatx4 accp[4][2] = {};
#pragma unroll
    for (int h = 0; h < 2; ++h) {
        __syncthreads();
        if (wn == h) {
#pragma unroll
            for (int i = 0; i < 8; ++i)
#pragma unroll
                for (int j = 0; j < 8; ++j) {
                    const int ct = j * 16 + r;
                    const int colg = bn * 256 + h * 128 + ct;
#pragma unroll
                    for (int rr = 0; rr < 4; ++rr) {
                        const int rowl = wm * 128 + i * 16 + r4 + rr;
                        const int rowg = bm * 256 + rowl;
                        float v = acc[i][j][rr];
                        const unsigned brow = (unsigned)rowg / 7u;
                        if (!(__bfloat162float(Y3h[(long)brow * WIDTH + colg]) > 0.f)) v = 0.f;
                        __half hb = __float2half(v);
                        T[rowl * 136 + ct] = *reinterpret_cast<short*>(&hb);
                    }
                }
        }
        {
            const int n = tid >> 4, k8 = (tid & 15) * 8;
            const short* wh = (const short*)Wcf;
            *reinterpret_cast<short8*>(&WcH[n * 136 + k8]) =
                *reinterpret_cast<const short8*>(wh + (long)n * WIDTH + bn * 256 + h * 128 + k8);
            *reinterpret_cast<short8*>(&WcH[(n + 16) * 136 + k8]) =
                *reinterpret_cast<const short8*>(wh + (long)(n + 16) * WIDTH + bn * 256 + h * 128 + k8);
        }
        __syncthreads();
#pragma unroll
        for (int kk = 0; kk < 128; kk += 32) {
            short8 af2[4], bh8[2];
#pragma unroll
            for (int i = 0; i < 4; ++i)
                af2[i] = *reinterpret_cast<const short8*>(&T[(wv * 64 + i * 16 + r) * 136 + kk + kq]);
#pragma unroll
            for (int j = 0; j < 2; ++j)
                bh8[j] = *reinterpret_cast<const short8*>(&WcH[(j * 16 + r) * 136 + kk + kq]);
#pragma unroll
            for (int i = 0; i < 4; ++i)
#pragma unroll
                for (int j = 0; j < 2; ++j)
                    accp[i][j] = mfma16(af2[i], bh8[j], accp[i][j]);
        }
    }
#pragma unroll
    for (int i = 0; i < 4; ++i)
#pragma unroll
        for (int j = 0; j < 2; ++j)
#pragma unroll
            for (int rr = 0; rr < 4; ++rr) {
                const int rowg = bm * 256 + wv * 64 + i * 16 + r4 + rr;
                PDpart[((long)bn * Mrows + rowg) * 32 + j * 16 + r] = accp[i][j][rr];
            }
}

// ---------------- finalize: 7x7 algebra; reduces PDpart inline ----------------
__device__ __forceinline__ int midx(int rr, int cc) {
    const int i = rr - cc;
    return i * 7 - (i * (i - 1)) / 2 + cc;
}

__global__ __launch_bounds__(64) void finalize_k(
    const float* __restrict__ PY,
    const float* __restrict__ PDpart,   // [4][Mrows][32]
    const float* __restrict__ vel_g,
    const float* __restrict__ acc_g,
    const float* __restrict__ b_ld,
    const float* __restrict__ b_lo,
    float* __restrict__ out,
    int b0, int Mrows)
{
    __shared__ float lval[28];
    __shared__ int gpv[7];
    __shared__ float derl[29 * 7];
    __shared__ float Lm[49], Mm[49], dLt[49], uu[49];
    __shared__ float wvv[7], pv[7], Cv[7], Gv[7], tauv[7], vl[7], ac[7];

    const int bl = blockIdx.x, tid = threadIdx.x;
    const int b = b0 + bl;
    if (tid < 28) {
        float s = PY[(long)bl * 32 + tid];
        if (tid < 7) {
            s += b_ld[tid];
            gpv[tid] = s > 0.f;
            lval[tid] = s > 0.f ? s : 0.f;
        } else {
            lval[tid] = s + b_lo[tid - 7];
        }
    }
    if (tid >= 28 && tid < 35) {
        vl[tid - 28] = vel_g[b * 7 + tid - 28];
        ac[tid - 28] = acc_g[b * 7 + tid - 28];
    }
    __syncthreads();
    for (int idx = tid; idx < 203; idx += 64) {
        const int m = idx / 7, d = idx % 7;
        float v = 0.f;
#pragma unroll
        for (int p = 0; p < 4; ++p)
            v += PDpart[((long)p * Mrows + bl * 7 + d) * 32 + m];
        if (m < 7 && !gpv[m]) v = 0.f;
        derl[m * 7 + d] = v;
    }
    __syncthreads();
    if (tid < 49) {
        const int rr = tid / 7, cc = tid % 7;
        Lm[tid] = (rr >= cc) ? lval[midx(rr, cc)] : 0.f;
    }
    __syncthreads();
    if (tid < 49) {
        const int rr = tid / 7, cc = tid % 7;
        float s = 0.f;
        for (int k = 0; k < 7; ++k) s += Lm[rr * 7 + k] * Lm[cc * 7 + k];
        if (rr == cc) s += 1e-5f;
        Mm[tid] = s;
        float t = 0.f;
        if (rr >= cc) {
            const int m = midx(rr, cc);
            for (int d = 0; d < 7; ++d) t += derl[m * 7 + d] * vl[d];
        }
        dLt[tid] = t;
        float u = 0.f;
        for (int r2 = cc; r2 < 7; ++r2) u += vl[r2] * derl[midx(r2, cc) * 7 + rr];
        uu[tid] = u;
    } else if (tid >= 49 && tid < 56) {
        const int j = tid - 49;
        float s = 0.f;
        for (int r2 = 0; r2 < 7; ++r2) s += Lm[r2 * 7 + j] * vl[r2];
        wvv[j] = s;
    }
    __syncthreads();
    if (tid < 7) {
        float s = 0.f;
        for (int r2 = 0; r2 < 7; ++r2) s += dLt[r2 * 7 + tid] * vl[r2];
        pv[tid] = s;
    }
    __syncthreads();
    if (tid < 7) {
        float s = 0.f, q = 0.f, md = 0.f;
        for (int c = 0; c < 7; ++c) {
            s += Lm[tid * 7 + c] * pv[c] + dLt[tid * 7 + c] * wvv[c];
            q += uu[tid * 7 + c] * wvv[c];
            md += Mm[tid * 7 + c] * ac[c];
        }
        Cv[tid] = s - q;
        Gv[tid] = derl[28 * 7 + tid];
        tauv[tid] = md + Cv[tid] + Gv[tid];
    }
    __syncthreads();
    if (tid < 49) out[57344 + (long)b * 49 + tid] = Mm[tid];
    if (tid < 7) {
        out[(long)b * 7 + tid] = tauv[tid];
        out[458752 + (long)b * 7 + tid] = Cv[tid];
        out[516096 + (long)b * 7 + tid] = Gv[tid];
    }
}

extern "C" void kernel_launch(void* const* d_in, const int* in_sizes, int n_in,
                              void* d_out, int out_size, void* d_ws, size_t ws_size,
                              hipStream_t stream)
{
    const float* state = (const float*)d_in[0];
    const float* vel   = (const float*)d_in[1];
    const float* accel = (const float*)d_in[2];
    const float* W_in  = (const float*)d_in[3];
    const float* b_in  = (const float*)d_in[4];
    const float* W_h   = (const float*)d_in[5];
    const float* b_h   = (const float*)d_in[6];
    const float* W_g   = (const float*)d_in[7];
    /* d_in[8] = b_g unused */
    const float* W_ld  = (const float*)d_in[9];
    const float* b_ld  = (const float*)d_in[10];
    const float* W_lo  = (const float*)d_in[11];
    const float* b_lo  = (const float*)d_in[12];
    float* outp = (float*)d_out;

    char* ws = (char*)d_ws;
    __hip_bfloat16* Wthb = (__hip_bfloat16*)ws; ws += (size_t)WIDTH * WIDTH * 2;
    __hip_bfloat16* Wtlb = (__hip_bfloat16*)ws; ws += (size_t)WIDTH * WIDTH * 2;
    __half*         Wtf  = (__half*)ws;         ws += (size_t)WIDTH * WIDTH * 2;
    __hip_bfloat16* Wchb = (__hip_bfloat16*)ws; ws += 32 * WIDTH * 2;
    __hip_bfloat16* Wclb = (__hip_bfloat16*)ws; ws += 32 * WIDTH * 2;
    __half*         Wcf  = (__half*)ws;         ws += 32 * WIDTH * 2;
    const size_t fixed = (size_t)(ws - (char*)d_ws);

    // per-sample: Y bf16 4*2048 + D1 f16 14336 + D2 f16 14336 + PY 128 = 36992 B
    int CH = 256;
    for (int cand = 8192; cand >= 256; cand >>= 1) {
        size_t need = fixed + (size_t)cand * 36992;
        if (need <= ws_size) { CH = cand; break; }
    }
    const int NCH = BATCH / CH;

    const size_t YB = (size_t)CH * WIDTH * 2;
    const size_t DB = (size_t)CH * 7 * WIDTH * 2;
    __hip_bfloat16* Yah = (__hip_bfloat16*)ws; ws += YB;   // Y1 -> Y3 hi
    __hip_bfloat16* Yal = (__hip_bfloat16*)ws; ws += YB;   // Y1 -> Y3 lo
    __hip_bfloat16* Ybh = (__hip_bfloat16*)ws; ws += YB;   // Y2 hi
    __hip_bfloat16* Ybl = (__hip_bfloat16*)ws; ws += YB;   // Y2 lo
    __half* Daf = (__half*)ws; ws += DB;                   // D1 (aliased as PDpart in D3 phase)
    __half* Dbf = (__half*)ws; ws += DB;                   // D2
    float* PY = (float*)ws; ws += (size_t)CH * 32 * 4;
    float* PDpart = (float*)Daf;   // 4*(7*CH)*32*4 = CH*3584 B <= DB

    const int Mrows = CH * 7;
    const int nd2 = Mrows / 256;    // 256-row D tiles (112 @ CH=4096, %8==0)
    const int ny128 = CH / 128;     // 128-row Y tiles (32 @ CH=4096, %8==0)

    transpose_k<<<dim3(32, 32), dim3(256), 0, stream>>>(W_h, Wthb, Wtlb, Wtf);
    buildwcat_k<<<dim3(128), dim3(256), 0, stream>>>(W_ld, W_lo, W_g, Wchb, Wclb, Wcf);

    for (int c = 0; c < NCH; ++c) {
        prep_k<<<dim3(CH), dim3(256), 0, stream>>>(state + (size_t)c * CH * 7, W_in, b_in,
                                                   Yah, Yal, Daf);
        gemm_y8<<<dim3(ny128 * 4), dim3(512), 0, stream>>>(
            Yah, Yal, Wthb, Wtlb, b_h, Ybh, Ybl, ny128);                        // Y2
        d2y3_8p<<<dim3((ny128 + nd2) * 4), dim3(512), 0, stream>>>(
            Daf, Wtf, Wthb, Wtlb, Ybh, Ybl, b_h, Dbf, Yah, Yal, ny128, nd2);    // Y3 + D2
        d3pd128<<<dim3(nd2 * 4 + ny128), dim3(256), 0, stream>>>(
            Dbf, Wtf, Yah, Yal, Wcf, Wchb, Wclb, PDpart, PY, nd2, Mrows);       // D3+PD + heady
        finalize_k<<<dim3(CH), dim3(64), 0, stream>>>(PY, PDpart, vel, accel, b_ld, b_lo,
                                                      outp, c * CH, Mrows);
    }
    (void)in_sizes; (void)n_in; (void)out_size;
}

// Round 12
// 550.982 us; speedup vs baseline: 1.3034x; 1.3034x over previous
//
#include <hip/hip_runtime.h>
#include <hip/hip_bf16.h>
#include <hip/hip_fp16.h>

#define WIDTH 1024
#define BATCH 8192

typedef __attribute__((ext_vector_type(8))) short short8;
typedef __attribute__((ext_vector_type(8))) _Float16 half8;
typedef __attribute__((ext_vector_type(4))) float floatx4;

typedef __attribute__((address_space(1))) void gvoid;
typedef __attribute__((address_space(3))) void lvoid;

__device__ __forceinline__ void async_copy16(const void* g, void* l) {
    __builtin_amdgcn_global_load_lds((gvoid*)g, (lvoid*)l, 16, 0, 0);
}

// bf16 hi/lo split store (residual exactly representable - no denormal risk)
__device__ __forceinline__ void split_store(float v, __hip_bfloat16* hi, __hip_bfloat16* lo, long idx) {
    __hip_bfloat16 h = __float2bfloat16(v);
    hi[idx] = h;
    lo[idx] = __float2bfloat16(v - __bfloat162float(h));
}

__device__ __forceinline__ floatx4 mfma16(short8 a, short8 b, floatx4 c) {
    return __builtin_amdgcn_mfma_f32_16x16x32_f16(
        __builtin_bit_cast(half8, a), __builtin_bit_cast(half8, b), c, 0, 0, 0);
}
__device__ __forceinline__ floatx4 mfmabf(short8 a, short8 b, floatx4 c) {
    return __builtin_amdgcn_mfma_f32_16x16x32_bf16(a, b, c, 0, 0, 0);
}

template<int N> __device__ __forceinline__ void waitv() {
    if constexpr (N == 0)      asm volatile("s_waitcnt vmcnt(0)" ::: "memory");
    else if constexpr (N == 4) asm volatile("s_waitcnt vmcnt(4)" ::: "memory");
    else if constexpr (N == 6) asm volatile("s_waitcnt vmcnt(6)" ::: "memory");
    else if constexpr (N == 8) asm volatile("s_waitcnt vmcnt(8)" ::: "memory");
}

// T2 swizzle (verified: bank conflicts -> 0)
__device__ __forceinline__ int swz_col(int s) {
    return ((s & 3) ^ ((s >> 3) & 3)) << 3;
}

// T1 XCD co-location map (verified r6: FETCH -30%)
__device__ __forceinline__ void xcd_map(int idx, int nm, int& bm, int& bn) {
    if ((nm & 7) == 0) {
        bm = (idx & 7) | ((idx >> 5) << 3);
        bn = (idx >> 3) & 3;
    } else {
        bm = idx >> 2;
        bn = idx & 3;
    }
}

// ---------------- transpose W_h (fp32) -> Wt bf16-split (Y path) + f16 (D path) ----------------
__global__ __launch_bounds__(256) void transpose_k(
    const float* __restrict__ W,
    __hip_bfloat16* __restrict__ Wthb, __hip_bfloat16* __restrict__ Wtlb,
    __half* __restrict__ Wtf)
{
    __shared__ float t[32][33];
    const int tx = threadIdx.x & 31, ty = threadIdx.x >> 5;
    const int bx = blockIdx.x << 5, by = blockIdx.y << 5;
#pragma unroll
    for (int r = 0; r < 32; r += 8)
        t[ty + r][tx] = W[(long)(by + ty + r) * WIDTH + bx + tx];
    __syncthreads();
#pragma unroll
    for (int r = 0; r < 32; r += 8) {
        const float v = t[tx][ty + r];
        const long idx = (long)(bx + ty + r) * WIDTH + by + tx;
        split_store(v, Wthb, Wtlb, idx);
        Wtf[idx] = __float2half(v);
    }
}

// ---------------- pack head weights: Wcat[32][1024] bf16-split + f16 ----------------
__global__ __launch_bounds__(256) void buildwcat_k(
    const float* __restrict__ W_ld, const float* __restrict__ W_lo,
    const float* __restrict__ W_g,
    __hip_bfloat16* __restrict__ Wchb, __hip_bfloat16* __restrict__ Wclb,
    __half* __restrict__ Wcf)
{
    const int idx = blockIdx.x * 256 + threadIdx.x;   // 32*1024
    const int n = idx >> 10, k = idx & 1023;
    float v = 0.f;
    if (n < 7)       v = W_ld[k * 7 + n];
    else if (n < 28) v = W_lo[k * 21 + (n - 7)];
    else if (n == 28) v = W_g[k];
    split_store(v, Wchb, Wclb, idx);
    Wcf[idx] = __float2half(v);
}

// ---------------- layer 1: Y1 bf16-split, D1 f16 ----------------
__global__ __launch_bounds__(256) void prep_k(
    const float* __restrict__ state,
    const float* __restrict__ W_in,
    const float* __restrict__ b_in,
    __hip_bfloat16* __restrict__ Y1h, __hip_bfloat16* __restrict__ Y1l,
    __half* __restrict__ D1f)
{
    const int b = blockIdx.x;
    const int j0 = threadIdx.x * 4;
    float s[7];
#pragma unroll
    for (int d = 0; d < 7; ++d) s[d] = state[b * 7 + d];
    float a[4];
#pragma unroll
    for (int q = 0; q < 4; ++q) a[q] = b_in[j0 + q];
    float w[7][4];
#pragma unroll
    for (int d = 0; d < 7; ++d)
#pragma unroll
        for (int q = 0; q < 4; ++q) {
            w[d][q] = W_in[d * WIDTH + j0 + q];
            a[q] += s[d] * w[d][q];
        }
    bool gp[4];
#pragma unroll
    for (int q = 0; q < 4; ++q) {
        gp[q] = a[q] > 0.f;
        split_store(gp[q] ? a[q] : 0.f, Y1h, Y1l, (long)b * WIDTH + j0 + q);
    }
    union { unsigned long long u64; unsigned short h[4]; } pk;
#pragma unroll
    for (int d = 0; d < 7; ++d) {
#pragma unroll
        for (int q = 0; q < 4; ++q) {
            __half v = __float2half(gp[q] ? w[d][q] : 0.f);
            pk.h[q] = *reinterpret_cast<unsigned short*>(&v);
        }
        *reinterpret_cast<unsigned long long*>(&D1f[((long)b * 7 + d) * WIDTH + j0]) = pk.u64;
    }
}

// ---------------- staging primitives (T2 pre-swizzled source) ----------------
__device__ __forceinline__ void st128(const short* src, short* region, int tid, int kbase) {
    async_copy16(src + (long)(tid >> 2) * WIDTH + kbase + swz_col(tid),
                 region + ((tid & 0x1C0) << 3));
}
__device__ __forceinline__ void st256(const short* src, short* region, int tid, int kbase) {
#pragma unroll
    for (int j = 0; j < 2; ++j) {
        const int idx = tid + (j << 9);
        async_copy16(src + (long)(idx >> 2) * WIDTH + kbase + swz_col(idx),
                     region + (((tid & 0x1C0) + (j << 9)) << 3));
    }
}

// ================= y8: 128x256 3-term bf16 GEMM, reg-pipelined, 3-buffer ring =================
// Chunk = K-32. Per chunk: 1 barrier; stage(c+3) [6 vm events]; ds_reads(c+1) into
// spare frag set; 48 MFMA on current set (compiler emits counted lgkm waits);
// vmcnt(6) [c<=28], vmcnt(0) [c==29]. Ring: 3 buffers x 24576 shorts (144 KB).
// Ledger verified: end-of-chunk-c vmcnt(6) => chunks <= c+2 landed => reads(c+1)
// in chunk c (after barrier) safe; stage(c+3) overwrites region(c) whose reads
// completed end of chunk c-1, published by chunk-c barrier.

__device__ __forceinline__ void y_stage(
    short* SM, const short* pAh, const short* pAl,
    const short* pBh, const short* pBl, int c, int tid)
{
    short* buf = SM + (c % 3) * 24576;
    const int kb = c * 32;
    st128(pAh, buf,         tid, kb);
    st256(pBh, buf + 8192,  tid, kb);
    st128(pAl, buf + 4096,  tid, kb);
    st256(pBl, buf + 16384, tid, kb);
}

__device__ __forceinline__ void y_reads(
    const short* SM, int c, int wm, int wn, int r, int kqs,
    short8 (&ah)[4], short8 (&al)[4], short8 (&bh)[4], short8 (&bl)[4])
{
    const short* buf = SM + (c % 3) * 24576;
#pragma unroll
    for (int i = 0; i < 4; ++i) {
        ah[i] = *reinterpret_cast<const short8*>(&buf[(wm * 64 + i * 16 + r) * 32 + kqs]);
        al[i] = *reinterpret_cast<const short8*>(&buf[4096 + (wm * 64 + i * 16 + r) * 32 + kqs]);
    }
#pragma unroll
    for (int j = 0; j < 4; ++j) {
        bh[j] = *reinterpret_cast<const short8*>(&buf[8192 + (wn * 64 + j * 16 + r) * 32 + kqs]);
        bl[j] = *reinterpret_cast<const short8*>(&buf[16384 + (wn * 64 + j * 16 + r) * 32 + kqs]);
    }
}

__device__ __forceinline__ void y8_gemm_body(
    short* SM,   // 73728 shorts (3 x 24576)
    int bm, int bn, int tid,
    const __hip_bfloat16* Ah_, const __hip_bfloat16* Al_,
    const __hip_bfloat16* Bh_, const __hip_bfloat16* Bl_,
    const float* bias,
    __hip_bfloat16* outh, __hip_bfloat16* outl)
{
    const int lane = tid & 63, wv = tid >> 6;
    const int wm = wv >> 2, wn = wv & 3;
    const int r = lane & 15, r4 = (lane >> 4) << 2;
    const int kqs = (((lane >> 4) ^ ((r >> 1) & 3)) << 3);
    const short* pAh = (const short*)Ah_ + (long)bm * 128 * WIDTH;
    const short* pAl = (const short*)Al_ + (long)bm * 128 * WIDTH;
    const short* pBh = (const short*)Bh_ + (long)bn * 256 * WIDTH;
    const short* pBl = (const short*)Bl_ + (long)bn * 256 * WIDTH;

    floatx4 acc[4][4] = {};
    short8 ahA[4], alA[4], bhA[4], blA[4];
    short8 ahB[4], alB[4], bhB[4], blB[4];

    y_stage(SM, pAh, pAl, pBh, pBl, 0, tid);
    y_stage(SM, pAh, pAl, pBh, pBl, 1, tid);
    y_stage(SM, pAh, pAl, pBh, pBl, 2, tid);
    waitv<6>();                                   // chunks 0,1 landed
    __builtin_amdgcn_s_barrier();
    y_reads(SM, 0, wm, wn, r, kqs, ahA, alA, bhA, blA);

    auto chunk = [&](short8 (&cah)[4], short8 (&cal)[4], short8 (&cbh)[4], short8 (&cbl)[4],
                     short8 (&nah)[4], short8 (&nal)[4], short8 (&nbh)[4], short8 (&nbl)[4],
                     int c) {
        __builtin_amdgcn_s_barrier();
        if (c + 3 < 32) y_stage(SM, pAh, pAl, pBh, pBl, c + 3, tid);
        if (c + 1 < 32) y_reads(SM, c + 1, wm, wn, r, kqs, nah, nal, nbh, nbl);
        __builtin_amdgcn_s_setprio(1);
#pragma unroll
        for (int i = 0; i < 4; ++i)
#pragma unroll
            for (int j = 0; j < 4; ++j)
                acc[i][j] = mfmabf(cah[i], cbh[j], acc[i][j]);
#pragma unroll
        for (int i = 0; i < 4; ++i)
#pragma unroll
            for (int j = 0; j < 4; ++j)
                acc[i][j] = mfmabf(cal[i], cbh[j], acc[i][j]);
#pragma unroll
        for (int i = 0; i < 4; ++i)
#pragma unroll
            for (int j = 0; j < 4; ++j)
                acc[i][j] = mfmabf(cah[i], cbl[j], acc[i][j]);
        __builtin_amdgcn_s_setprio(0);
        if (c <= 28) waitv<6>();
        else if (c == 29) waitv<0>();
    };

    for (int t2 = 0; t2 < 16; ++t2) {
        chunk(ahA, alA, bhA, blA, ahB, alB, bhB, blB, 2 * t2);
        chunk(ahB, alB, bhB, blB, ahA, alA, bhA, blA, 2 * t2 + 1);
    }

    // epilogue: bias + relu + split store
#pragma unroll
    for (int i = 0; i < 4; ++i)
#pragma unroll
        for (int j = 0; j < 4; ++j) {
            const int col = bn * 256 + wn * 64 + j * 16 + r;
#pragma unroll
            for (int rr = 0; rr < 4; ++rr) {
                const int row = bm * 128 + wm * 64 + i * 16 + r4 + rr;
                float v = acc[i][j][rr] + bias[col];
                v = v > 0.f ? v : 0.f;
                split_store(v, outh, outl, (long)row * WIDTH + col);
            }
        }
}

// ---------------- Y2 GEMM (standalone, y8, XCD-mapped 1-D grid) ----------------
__global__ __launch_bounds__(512, 2) void gemm_y8(
    const __hip_bfloat16* __restrict__ Ah, const __hip_bfloat16* __restrict__ Al,
    const __hip_bfloat16* __restrict__ Bh, const __hip_bfloat16* __restrict__ Bl,
    const float* __restrict__ bias,
    __hip_bfloat16* __restrict__ outh, __hip_bfloat16* __restrict__ outl,
    int ny)
{
    __shared__ __align__(16) short SM[73728];
    int bm, bn;
    xcd_map(blockIdx.x, ny, bm, bn);
    y8_gemm_body(SM, bm, bn, threadIdx.x, Ah, Al, Bh, Bl, bias, outh, outl);
}

// ================= 256x256 1-pass f16 D-GEMM, reg-pipelined, 8-region ring =================
// Chunk = K-32 (c = 0..31). Region: buffer (c>>1)&1, A at (c&1)<<14, B at +8192.
// Per chunk: 1 barrier; stage(c+4) [4 vm events]; ds_reads(c+1) into spare frag set;
// 32 MFMA on current; vmcnt(8) [c<=27], (4) [c==28], (0) [c==29].
// Ledger verified: end-of-chunk-c vmcnt(8) => chunks <= c+2 landed.

__device__ __forceinline__ void stage_chunk_d2(
    short* SMbase, const short* __restrict__ A, const short* __restrict__ B,
    int tau, int creg, int tid)
{
    const short* src = (creg & 1) ? B : A;
    const int kbase = (tau << 6) + ((creg >> 1) << 5);
    short* region = SMbase + ((tau & 1) << 15) + (creg << 13);
    const int wvb = tid & 0x1C0;
#pragma unroll
    for (int j = 0; j < 2; ++j) {
        const int idx = tid + (j << 9);
        async_copy16(src + (long)(idx >> 2) * WIDTH + kbase + swz_col(idx),
                     region + ((long)(wvb + (j << 9)) << 3));
    }
}

__device__ __forceinline__ void d_stage(
    short* SM, const short* A, const short* B, int c, int tid)
{
    stage_chunk_d2(SM, A, B, c >> 1, (c & 1) << 1, tid);
    stage_chunk_d2(SM, A, B, c >> 1, ((c & 1) << 1) | 1, tid);
}

__device__ __forceinline__ void d_reads(
    const short* SM, int c, int wm, int wn, int r, int kqs,
    short8 (&af)[8], short8 (&bf)[4])
{
    const short* Ab = SM + (((c >> 1) & 1) << 15) + ((c & 1) << 14);
    const short* Bb = Ab + 8192;
#pragma unroll
    for (int i = 0; i < 8; ++i)
        af[i] = *reinterpret_cast<const short8*>(&Ab[(wm * 128 + i * 16 + r) * 32 + kqs]);
#pragma unroll
    for (int j = 0; j < 4; ++j)
        bf[j] = *reinterpret_cast<const short8*>(&Bb[(wn * 64 + j * 16 + r) * 32 + kqs]);
}

__device__ __forceinline__ void d_gemm_256(
    short* SM, const short* Abase, const short* Bbase, int tid,
    int wm, int wn, int r, int kqs, floatx4 (&acc)[8][4])
{
    short8 afA[8], bfA[4], afB[8], bfB[4];

    d_stage(SM, Abase, Bbase, 0, tid);
    d_stage(SM, Abase, Bbase, 1, tid);
    d_stage(SM, Abase, Bbase, 2, tid);
    d_stage(SM, Abase, Bbase, 3, tid);
    waitv<8>();                                   // chunks 0,1 landed
    __builtin_amdgcn_s_barrier();
    d_reads(SM, 0, wm, wn, r, kqs, afA, bfA);

    auto chunk = [&](short8 (&caf)[8], short8 (&cbf)[4],
                     short8 (&naf)[8], short8 (&nbf)[4], int c) {
        __builtin_amdgcn_s_barrier();
        if (c + 4 < 32) d_stage(SM, Abase, Bbase, c + 4, tid);
        if (c + 1 < 32) d_reads(SM, c + 1, wm, wn, r, kqs, naf, nbf);
        __builtin_amdgcn_s_setprio(1);
#pragma unroll
        for (int i = 0; i < 8; ++i)
#pragma unroll
            for (int j = 0; j < 4; ++j)
                acc[i][j] = mfma16(caf[i], cbf[j], acc[i][j]);
        __builtin_amdgcn_s_setprio(0);
        if (c <= 27) waitv<8>();
        else if (c == 28) waitv<4>();
        else if (c == 29) waitv<0>();
    };

    for (int t2 = 0; t2 < 16; ++t2) {
        chunk(afA, bfA, afB, bfB, 2 * t2);
        chunk(afB, bfB, afA, bfA, 2 * t2 + 1);
    }
}

// ================= fused Y3 (y8, dispatched FIRST) + D2 (f16, XCD-mapped) =================
__global__ __launch_bounds__(512, 2) void d2y3_8p(
    const __half* __restrict__ D1,
    const __half* __restrict__ Wtf,
    const __hip_bfloat16* __restrict__ Wthb, const __hip_bfloat16* __restrict__ Wtlb,
    const __hip_bfloat16* __restrict__ Y2h, const __hip_bfloat16* __restrict__ Y2l,
    const float* __restrict__ bias,
    __half* __restrict__ D2out,
    __hip_bfloat16* __restrict__ Y3h, __hip_bfloat16* __restrict__ Y3l,
    int ny128, int nd2)
{
    __shared__ __align__(16) short SM[73728];   // 144 KiB (y8 ring); D uses first 128 KiB
    const int tid = threadIdx.x;

    if ((int)blockIdx.x < ny128 * 4) {
        int bm, bn;
        xcd_map(blockIdx.x, ny128, bm, bn);
        y8_gemm_body(SM, bm, bn, tid, Y2h, Y2l, Wthb, Wtlb, bias, Y3h, Y3l);
        return;
    }

    const int lane = tid & 63, wv = tid >> 6;
    const int wm = wv >> 2, wn = wv & 3;
    const int r = lane & 15, r4 = (lane >> 4) << 2;
    const int kqs = (((lane >> 4) ^ ((r >> 1) & 3)) << 3);

    int bm, bn;
    xcd_map(blockIdx.x - ny128 * 4, nd2, bm, bn);

    floatx4 acc[8][4] = {};
    d_gemm_256(SM, (const short*)D1 + (long)bm * 256 * WIDTH,
               (const short*)Wtf + (long)bn * 256 * WIDTH, tid, wm, wn, r, kqs, acc);

    // epilogue: relu'(Y2) mask, store f16
#pragma unroll
    for (int i = 0; i < 8; ++i)
#pragma unroll
        for (int j = 0; j < 4; ++j) {
            const int col = bn * 256 + wn * 64 + j * 16 + r;
#pragma unroll
            for (int rr = 0; rr < 4; ++rr) {
                const int row = bm * 256 + wm * 128 + i * 16 + r4 + rr;
                float v = acc[i][j][rr];
                const unsigned brow = (unsigned)row / 7u;
                if (!(__bfloat162float(Y2h[(long)brow * WIDTH + col]) > 0.f)) v = 0.f;
                D2out[(long)row * WIDTH + col] = __float2half(v);
            }
        }
}

// ---------------- heady half body (128-row Y3 @ Wcat^T, 3-term bf16) ----------------
__device__ __forceinline__ void heady_half(
    short* SMh, int bm, int tl,
    const __hip_bfloat16* __restrict__ Y3h, const __hip_bfloat16* __restrict__ Y3l,
    const __hip_bfloat16* __restrict__ Wch, const __hip_bfloat16* __restrict__ Wcl,
    float* __restrict__ PY)
{
    short* Ash = SMh;          short* Asl = SMh + 4096;
    short* Bsh = SMh + 8192;   short* Bsl = SMh + 9216;
    const int lane = tl & 63;
    const int wv = tl >> 6;
    const int r = lane & 15, r4 = (lane >> 4) << 2;
    const int kqs = (((lane >> 4) ^ ((r >> 1) & 3)) << 3);
    const int srow = tl >> 2, scol = (tl & 3) << 3;
    const int swc = (((tl & 3) ^ ((srow >> 1) & 3)) << 3);
    const long half = 64l * WIDTH;
    const short* pAh = (const short*)Y3h + (long)(bm * 128 + srow) * WIDTH + swc;
    const short* pAl = (const short*)Y3l + (long)(bm * 128 + srow) * WIDTH + swc;
    const long boff = (long)srow * WIDTH + scol;
    const short* pBh = (const short*)Wch;  const short* pBl = (const short*)Wcl;

    floatx4 acc[2][2] = {};
    for (int kt = 0; kt < WIDTH; kt += 32) {
        short8 gbh, gbl;
        if (tl < 128) {
            gbh = *reinterpret_cast<const short8*>(pBh + boff + kt);
            gbl = *reinterpret_cast<const short8*>(pBl + boff + kt);
        }
        __syncthreads();
        async_copy16(pAh + kt,        Ash + wv * 512);
        async_copy16(pAh + half + kt, Ash + 2048 + wv * 512);
        async_copy16(pAl + kt,        Asl + wv * 512);
        async_copy16(pAl + half + kt, Asl + 2048 + wv * 512);
        if (tl < 128) {
            *reinterpret_cast<short8*>(&Bsh[srow * 32 + swc]) = gbh;
            *reinterpret_cast<short8*>(&Bsl[srow * 32 + swc]) = gbl;
        }
        __syncthreads();
        short8 afh[2], afl[2], bfh[2], bfl[2];
#pragma unroll
        for (int i = 0; i < 2; ++i) {
            const int ar = (wv * 32 + i * 16 + r) * 32 + kqs;
            afh[i] = *reinterpret_cast<const short8*>(&Ash[ar]);
            afl[i] = *reinterpret_cast<const short8*>(&Asl[ar]);
        }
#pragma unroll
        for (int j = 0; j < 2; ++j) {
            const int br = (j * 16 + r) * 32 + kqs;
            bfh[j] = *reinterpret_cast<const short8*>(&Bsh[br]);
            bfl[j] = *reinterpret_cast<const short8*>(&Bsl[br]);
        }
#pragma unroll
        for (int i = 0; i < 2; ++i)
#pragma unroll
            for (int j = 0; j < 2; ++j) {
                acc[i][j] = mfmabf(afh[i], bfh[j], acc[i][j]);
                acc[i][j] = mfmabf(afh[i], bfl[j], acc[i][j]);
                acc[i][j] = mfmabf(afl[i], bfh[j], acc[i][j]);
            }
    }
#pragma unroll
    for (int i = 0; i < 2; ++i)
#pragma unroll
        for (int j = 0; j < 2; ++j)
#pragma unroll
            for (int rr = 0; rr < 4; ++rr) {
                const int row = bm * 128 + wv * 32 + i * 16 + r4 + rr;
                PY[(long)row * 32 + j * 16 + r] = acc[i][j][rr];
            }
}

// ================= fused D3 (f16, XCD-mapped, FIRST) + PD projection (f16) + heady =================
__global__ __launch_bounds__(512, 2) void d3pd_8p(
    const __half* __restrict__ D2,
    const __half* __restrict__ Wtf,
    const __hip_bfloat16* __restrict__ Y3h, const __hip_bfloat16* __restrict__ Y3l,
    const __half* __restrict__ Wcf,
    const __hip_bfloat16* __restrict__ Wchb, const __hip_bfloat16* __restrict__ Wclb,
    float* __restrict__ PDpart, float* __restrict__ PY,
    int nd2, int Mrows)
{
    __shared__ __align__(16) short SM[65536];
    const int tid = threadIdx.x;

    if ((int)blockIdx.x >= nd2 * 4) {
        const int hd = (blockIdx.x - nd2 * 4) * 2 + (tid >> 8);
        heady_half(SM + (tid >> 8) * 10240, hd, tid & 255, Y3h, Y3l, Wchb, Wclb, PY);
        return;
    }

    const int lane = tid & 63, wv = tid >> 6;
    const int wm = wv >> 2, wn = wv & 3;
    const int r = lane & 15, kq = (lane >> 4) << 3, r4 = (lane >> 4) << 2;
    const int kqs = (((lane >> 4) ^ ((r >> 1) & 3)) << 3);
    int bm, bn;
    xcd_map(blockIdx.x, nd2, bm, bn);

    floatx4 acc[8][4] = {};
    d_gemm_256(SM, (const short*)D2 + (long)bm * 256 * WIDTH,
               (const short*)Wtf + (long)bn * 256 * WIDTH, tid, wm, wn, r, kqs, acc);

    // ---- fused PD projection: two col-half rounds through LDS (f16 T, f16 Wc) ----
    short* T   = SM;             // 256 x 136
    short* WcH = SM + 34816;     // 32 x 136

    floatx4 accp[2][2] = {};
#pragma unroll
    for (int h = 0; h < 2; ++h) {
        __syncthreads();
        if ((wn >> 1) == h) {
#pragma unroll
            for (int i = 0; i < 8; ++i)
#pragma unroll
                for (int j = 0; j < 4; ++j) {
                    const int ct = (wn & 1) * 64 + j * 16 + r;
                    const int colg = bn * 256 + h * 128 + ct;
#pragma unroll
                    for (int rr = 0; rr < 4; ++rr) {
                        const int rowl = wm * 128 + i * 16 + r4 + rr;
                        const int rowg = bm * 256 + rowl;
                        float v = acc[i][j][rr];
                        const unsigned brow = (unsigned)rowg / 7u;
                        if (!(__bfloat162float(Y3h[(long)brow * WIDTH + colg]) > 0.f)) v = 0.f;
                        __half hb = __float2half(v);
                        T[rowl * 136 + ct] = *reinterpret_cast<short*>(&hb);
                    }
                }
        }
        {
            const int n = tid >> 4, k8 = (tid & 15) * 8;
            const short* wh = (const short*)Wcf;
            *reinterpret_cast<short8*>(&WcH[n * 136 + k8]) =
                *reinterpret_cast<const short8*>(wh + (long)n * WIDTH + bn * 256 + h * 128 + k8);
        }
        __syncthreads();
#pragma unroll
        for (int kk = 0; kk < 128; kk += 32) {
            short8 af2[2], bh8[2];
#pragma unroll
            for (int i = 0; i < 2; ++i)
                af2[i] = *reinterpret_cast<const short8*>(&T[(wv * 32 + i * 16 + r) * 136 + kk + kq]);
#pragma unroll
            for (int j = 0; j < 2; ++j)
                bh8[j] = *reinterpret_cast<const short8*>(&WcH[(j * 16 + r) * 136 + kk + kq]);
#pragma unroll
            for (int i = 0; i < 2; ++i)
#pragma unroll
                for (int j = 0; j < 2; ++j)
                    accp[i][j] = mfma16(af2[i], bh8[j], accp[i][j]);
        }
    }
#pragma unroll
    for (int i = 0; i < 2; ++i)
#pragma unroll
        for (int j = 0; j < 2; ++j)
#pragma unroll
            for (int rr = 0; rr < 4; ++rr) {
                const int rowg = bm * 256 + wv * 32 + i * 16 + r4 + rr;
                PDpart[((long)bn * Mrows + rowg) * 32 + j * 16 + r] = accp[i][j][rr];
            }
}

// ---------------- finalize: 7x7 algebra; reduces PDpart inline ----------------
__device__ __forceinline__ int midx(int rr, int cc) {
    const int i = rr - cc;
    return i * 7 - (i * (i - 1)) / 2 + cc;
}

__global__ __launch_bounds__(64) void finalize_k(
    const float* __restrict__ PY,
    const float* __restrict__ PDpart,   // [4][Mrows][32]
    const float* __restrict__ vel_g,
    const float* __restrict__ acc_g,
    const float* __restrict__ b_ld,
    const float* __restrict__ b_lo,
    float* __restrict__ out,
    int b0, int Mrows)
{
    __shared__ float lval[28];
    __shared__ int gpv[7];
    __shared__ float derl[29 * 7];
    __shared__ float Lm[49], Mm[49], dLt[49], uu[49];
    __shared__ float wvv[7], pv[7], Cv[7], Gv[7], tauv[7], vl[7], ac[7];

    const int bl = blockIdx.x, tid = threadIdx.x;
    const int b = b0 + bl;
    if (tid < 28) {
        float s = PY[(long)bl * 32 + tid];
        if (tid < 7) {
            s += b_ld[tid];
            gpv[tid] = s > 0.f;
            lval[tid] = s > 0.f ? s : 0.f;
        } else {
            lval[tid] = s + b_lo[tid - 7];
        }
    }
    if (tid >= 28 && tid < 35) {
        vl[tid - 28] = vel_g[b * 7 + tid - 28];
        ac[tid - 28] = acc_g[b * 7 + tid - 28];
    }
    __syncthreads();
    for (int idx = tid; idx < 203; idx += 64) {
        const int m = idx / 7, d = idx % 7;
        float v = 0.f;
#pragma unroll
        for (int p = 0; p < 4; ++p)
            v += PDpart[((long)p * Mrows + bl * 7 + d) * 32 + m];
        if (m < 7 && !gpv[m]) v = 0.f;
        derl[m * 7 + d] = v;
    }
    __syncthreads();
    if (tid < 49) {
        const int rr = tid / 7, cc = tid % 7;
        Lm[tid] = (rr >= cc) ? lval[midx(rr, cc)] : 0.f;
    }
    __syncthreads();
    if (tid < 49) {
        const int rr = tid / 7, cc = tid % 7;
        float s = 0.f;
        for (int k = 0; k < 7; ++k) s += Lm[rr * 7 + k] * Lm[cc * 7 + k];
        if (rr == cc) s += 1e-5f;
        Mm[tid] = s;
        float t = 0.f;
        if (rr >= cc) {
            const int m = midx(rr, cc);
            for (int d = 0; d < 7; ++d) t += derl[m * 7 + d] * vl[d];
        }
        dLt[tid] = t;
        float u = 0.f;
        for (int r2 = cc; r2 < 7; ++r2) u += vl[r2] * derl[midx(r2, cc) * 7 + rr];
        uu[tid] = u;
    } else if (tid >= 49 && tid < 56) {
        const int j = tid - 49;
        float s = 0.f;
        for (int r2 = 0; r2 < 7; ++r2) s += Lm[r2 * 7 + j] * vl[r2];
        wvv[j] = s;
    }
    __syncthreads();
    if (tid < 7) {
        float s = 0.f;
        for (int r2 = 0; r2 < 7; ++r2) s += dLt[r2 * 7 + tid] * vl[r2];
        pv[tid] = s;
    }
    __syncthreads();
    if (tid < 7) {
        float s = 0.f, q = 0.f, md = 0.f;
        for (int c = 0; c < 7; ++c) {
            s += Lm[tid * 7 + c] * pv[c] + dLt[tid * 7 + c] * wvv[c];
            q += uu[tid * 7 + c] * wvv[c];
            md += Mm[tid * 7 + c] * ac[c];
        }
        Cv[tid] = s - q;
        Gv[tid] = derl[28 * 7 + tid];
        tauv[tid] = md + Cv[tid] + Gv[tid];
    }
    __syncthreads();
    if (tid < 49) out[57344 + (long)b * 49 + tid] = Mm[tid];
    if (tid < 7) {
        out[(long)b * 7 + tid] = tauv[tid];
        out[458752 + (long)b * 7 + tid] = Cv[tid];
        out[516096 + (long)b * 7 + tid] = Gv[tid];
    }
}

extern "C" void kernel_launch(void* const* d_in, const int* in_sizes, int n_in,
                              void* d_out, int out_size, void* d_ws, size_t ws_size,
                              hipStream_t stream)
{
    const float* state = (const float*)d_in[0];
    const float* vel   = (const float*)d_in[1];
    const float* accel = (const float*)d_in[2];
    const float* W_in  = (const float*)d_in[3];
    const float* b_in  = (const float*)d_in[4];
    const float* W_h   = (const float*)d_in[5];
    const float* b_h   = (const float*)d_in[6];
    const float* W_g   = (const float*)d_in[7];
    /* d_in[8] = b_g unused */
    const float* W_ld  = (const float*)d_in[9];
    const float* b_ld  = (const float*)d_in[10];
    const float* W_lo  = (const float*)d_in[11];
    const float* b_lo  = (const float*)d_in[12];
    float* outp = (float*)d_out;

    char* ws = (char*)d_ws;
    __hip_bfloat16* Wthb = (__hip_bfloat16*)ws; ws += (size_t)WIDTH * WIDTH * 2;
    __hip_bfloat16* Wtlb = (__hip_bfloat16*)ws; ws += (size_t)WIDTH * WIDTH * 2;
    __half*         Wtf  = (__half*)ws;         ws += (size_t)WIDTH * WIDTH * 2;
    __hip_bfloat16* Wchb = (__hip_bfloat16*)ws; ws += 32 * WIDTH * 2;
    __hip_bfloat16* Wclb = (__hip_bfloat16*)ws; ws += 32 * WIDTH * 2;
    __half*         Wcf  = (__half*)ws;         ws += 32 * WIDTH * 2;
    const size_t fixed = (size_t)(ws - (char*)d_ws);

    // per-sample: Y bf16 4*2048 + D1 f16 14336 + D2 f16 14336 + PY 128 = 36992 B
    int CH = 256;
    for (int cand = 8192; cand >= 256; cand >>= 1) {
        size_t need = fixed + (size_t)cand * 36992;
        if (need <= ws_size) { CH = cand; break; }
    }
    const int NCH = BATCH / CH;

    const size_t YB = (size_t)CH * WIDTH * 2;
    const size_t DB = (size_t)CH * 7 * WIDTH * 2;
    __hip_bfloat16* Yah = (__hip_bfloat16*)ws; ws += YB;   // Y1 -> Y3 hi
    __hip_bfloat16* Yal = (__hip_bfloat16*)ws; ws += YB;   // Y1 -> Y3 lo
    __hip_bfloat16* Ybh = (__hip_bfloat16*)ws; ws += YB;   // Y2 hi
    __hip_bfloat16* Ybl = (__hip_bfloat16*)ws; ws += YB;   // Y2 lo
    __half* Daf = (__half*)ws; ws += DB;                   // D1 (aliased as PDpart in D3 phase)
    __half* Dbf = (__half*)ws; ws += DB;                   // D2
    float* PY = (float*)ws; ws += (size_t)CH * 32 * 4;
    float* PDpart = (float*)Daf;   // 4*(7*CH)*32*4 = CH*3584 B <= DB

    const int Mrows = CH * 7;
    const int nd2 = Mrows / 256;    // 256-row D tiles
    const int ny128 = CH / 128;     // 128-row Y tiles

    transpose_k<<<dim3(32, 32), dim3(256), 0, stream>>>(W_h, Wthb, Wtlb, Wtf);
    buildwcat_k<<<dim3(128), dim3(256), 0, stream>>>(W_ld, W_lo, W_g, Wchb, Wclb, Wcf);

    for (int c = 0; c < NCH; ++c) {
        prep_k<<<dim3(CH), dim3(256), 0, stream>>>(state + (size_t)c * CH * 7, W_in, b_in,
                                                   Yah, Yal, Daf);
        gemm_y8<<<dim3(ny128 * 4), dim3(512), 0, stream>>>(
            Yah, Yal, Wthb, Wtlb, b_h, Ybh, Ybl, ny128);                        // Y2
        d2y3_8p<<<dim3((ny128 + nd2) * 4), dim3(512), 0, stream>>>(
            Daf, Wtf, Wthb, Wtlb, Ybh, Ybl, b_h, Dbf, Yah, Yal, ny128, nd2);    // Y3 + D2
        d3pd_8p<<<dim3(nd2 * 4 + ny128 / 2), dim3(512), 0, stream>>>(
            Dbf, Wtf, Yah, Yal, Wcf, Wchb, Wclb, PDpart, PY, nd2, Mrows);       // D3+PD + heady
        finalize_k<<<dim3(CH), dim3(64), 0, stream>>>(PY, PDpart, vel, accel, b_ld, b_lo,
                                                      outp, c * CH, Mrows);
    }
    (void)in_sizes; (void)n_in; (void)out_size;
}